// Round 4
// baseline (150.555 us; speedup 1.0000x reference)
//
#include <hip/hip_runtime.h>
#include <hip/hip_bf16.h>

#define DIMC 512
#define SEQ 4096
#define M_TOK 16384
#define N_QKV 1536

typedef __bf16 bfv8 __attribute__((ext_vector_type(8)));
typedef float f32v4 __attribute__((ext_vector_type(4)));
typedef unsigned short u16v8 __attribute__((ext_vector_type(8)));

static __device__ __forceinline__ float bf2f(unsigned short u) {
    union { unsigned int i; float f; } x; x.i = ((unsigned int)u) << 16; return x.f;
}
static __device__ __forceinline__ unsigned short f2bf(float f) {
    union { float f; unsigned int i; } x; x.f = f;
    unsigned int r = x.i + 0x7FFFu + ((x.i >> 16) & 1u);
    return (unsigned short)(r >> 16);
}

// ---------------- fp32 -> bf16 conversion (weights only) ----------------
__global__ __launch_bounds__(256) void cvt_f32_bf16(
    const float* __restrict__ in, unsigned short* __restrict__ out, int n8)
{
    int i = blockIdx.x * blockDim.x + threadIdx.x;
    if (i >= n8) return;
    const float4* p = (const float4*)in + (size_t)i * 2;
    float4 a = p[0], b = p[1];
    u16v8 o;
    o[0] = f2bf(a.x); o[1] = f2bf(a.y); o[2] = f2bf(a.z); o[3] = f2bf(a.w);
    o[4] = f2bf(b.x); o[5] = f2bf(b.y); o[6] = f2bf(b.z); o[7] = f2bf(b.w);
    *(u16v8*)(out + (size_t)i * 8) = o;
}

// ---------------- fully fused: qkv GEMM + head-mix attn + out GEMM ----------
// Block = 32 tokens, 512 threads (8 waves). X-tile + Y-tile in LDS; W
// operands streamed direct from L2 (L2-resident, no intra-block reuse to
// exploit). Swizzle: elem ^= (row&7)<<3  (byte-level (row&7)<<4, G4 fix).
__global__ __launch_bounds__(512) void fused_attn(
    const float* __restrict__ X,           // [16384][512] f32
    const unsigned short* __restrict__ Wq, // [1536][512] bf16
    const float* __restrict__ qkv_b,       // [1536] f32
    const unsigned short* __restrict__ Wo, // [512][512] bf16
    const float* __restrict__ out_b,       // [512] f32
    float* __restrict__ Out)               // [16384][512] f32
{
    __shared__ __align__(16) unsigned short Xs[32 * 512];   // 32KB, reused as Z
    __shared__ __align__(16) unsigned short Ys[32 * 1536];  // 96KB
    const int tid  = threadIdx.x;
    const int lane = tid & 63;
    const int wid  = tid >> 6;
    const int blk  = blockIdx.x;
    const int T0   = blk * 32;
    const int frow = lane & 15;
    const int fcol = (lane >> 4) * 8;
    const int erow = (lane >> 4) * 4;
    const int ecol = lane & 15;

    // ---------- Phase 0: X fp32 -> bf16, stage into LDS (2 column-halves) ----
    u16v8 xh[2][2];
    #pragma unroll
    for (int hh = 0; hh < 2; ++hh)
        #pragma unroll
        for (int it = 0; it < 2; ++it) {
            const int row = it * 16 + (tid >> 5);
            const int col = hh * 256 + (tid & 31) * 8;
            const float4* p = (const float4*)(X + (size_t)(T0 + row) * DIMC + col);
            float4 a = p[0], b = p[1];
            u16v8 o;
            o[0] = f2bf(a.x); o[1] = f2bf(a.y); o[2] = f2bf(a.z); o[3] = f2bf(a.w);
            o[4] = f2bf(b.x); o[5] = f2bf(b.y); o[6] = f2bf(b.z); o[7] = f2bf(b.w);
            xh[hh][it] = o;
        }
    #pragma unroll
    for (int it = 0; it < 2; ++it) {
        const int row = it * 16 + (tid >> 5);
        const int col = (tid & 31) * 8;
        *(u16v8*)&Xs[(row * DIMC + col) ^ ((row & 7) << 3)] = xh[0][it];
    }
    __syncthreads();

    // ---------- Phase 1: qkv GEMM. Per wave: 32 rows x 192 cols ----------
    const int n0 = wid * 192;
    f32v4 acc[2][12] = {};

#define QKV_STEP(kk)                                                            \
    {                                                                           \
        bfv8 bf[12];                                                            \
        _Pragma("unroll") for (int nf = 0; nf < 12; ++nf)                       \
            bf[nf] = *(const bfv8*)(Wq +                                        \
                (size_t)(n0 + nf * 16 + frow) * DIMC + (kk) * 32 + fcol);       \
        bfv8 af[2];                                                             \
        _Pragma("unroll") for (int m = 0; m < 2; ++m) {                         \
            const int r = m * 16 + frow;                                        \
            af[m] = *(const bfv8*)&Xs[(r * DIMC + (kk) * 32 + fcol) ^           \
                                      ((r & 7) << 3)];                          \
        }                                                                       \
        _Pragma("unroll") for (int m = 0; m < 2; ++m)                           \
        _Pragma("unroll") for (int nf = 0; nf < 12; ++nf)                       \
            acc[m][nf] = __builtin_amdgcn_mfma_f32_16x16x32_bf16(               \
                af[m], bf[nf], acc[m][nf], 0, 0, 0);                            \
    }

    #pragma unroll 1
    for (int kk = 0; kk < 8; ++kk) QKV_STEP(kk)
    // stage second column-half while first half computes
    #pragma unroll
    for (int it = 0; it < 2; ++it) {
        const int row = it * 16 + (tid >> 5);
        const int col = 256 + (tid & 31) * 8;
        *(u16v8*)&Xs[(row * DIMC + col) ^ ((row & 7) << 3)] = xh[1][it];
    }
    __syncthreads();
    #pragma unroll 1
    for (int kk = 8; kk < 16; ++kk) QKV_STEP(kk)
#undef QKV_STEP

    // epilogue -> Ys (bf16, +bias). D layout: row=(lane>>4)*4+r, col=lane&15.
    #pragma unroll
    for (int nf = 0; nf < 12; ++nf) {
        const int col = n0 + nf * 16 + ecol;
        const float bv = qkv_b[col];
        #pragma unroll
        for (int m = 0; m < 2; ++m)
            #pragma unroll
            for (int r = 0; r < 4; ++r) {
                const int row = m * 16 + erow + r;
                Ys[(row * N_QKV + col) ^ ((row & 7) << 3)] = f2bf(acc[m][nf][r] + bv);
            }
    }
    __syncthreads();

    // ---------- Phase 2: per-token 8x8 head-mix attention ----------
    // thread = (tok, h, d-half): tid = tok*16 + h*2 + half. All 512 active.
    {
        const int tok  = tid >> 4;
        const int h    = (tid >> 1) & 7;
        const int half = tid & 1;
        const int tsw  = (tok & 7) << 3;
        // q (this thread's 32-d half) -> f32
        float qf[32];
        #pragma unroll
        for (int c = 0; c < 4; ++c) {
            u16v8 v = *(const u16v8*)&Ys[(tok * N_QKV + h * 64 + half * 32 + c * 8) ^ tsw];
            #pragma unroll
            for (int j = 0; j < 8; ++j) qf[c * 8 + j] = bf2f(v[j]);
        }
        float sc[8];
        #pragma unroll
        for (int g = 0; g < 8; ++g) {
            float a = 0.f;
            const int kcol = DIMC + g * 64 + half * 32;
            #pragma unroll
            for (int c = 0; c < 4; ++c) {
                u16v8 v = *(const u16v8*)&Ys[(tok * N_QKV + kcol + c * 8) ^ tsw];
                #pragma unroll
                for (int j = 0; j < 8; ++j) a = fmaf(qf[c * 8 + j], bf2f(v[j]), a);
            }
            a += __shfl_xor(a, 1);   // combine the two d-halves (lane pair)
            sc[g] = a * 0.125f;
        }
        float mx = sc[0];
        #pragma unroll
        for (int g = 1; g < 8; ++g) mx = fmaxf(mx, sc[g]);
        float sum = 0.f;
        #pragma unroll
        for (int g = 0; g < 8; ++g) { sc[g] = __expf(sc[g] - mx); sum += sc[g]; }
        const float inv = 1.f / sum;
        #pragma unroll
        for (int g = 0; g < 8; ++g) sc[g] *= inv;
        // PV for this d-half; write Z (=Xs) in scrambled-row layout:
        // zrow = h*4 + tok/8, zcol = (tok%8)*64 + d
        const int zrow = h * 4 + (tok >> 3);
        const int zsw  = (zrow & 7) << 3;
        #pragma unroll
        for (int c = 0; c < 4; ++c) {
            float o[8] = {};
            #pragma unroll
            for (int g = 0; g < 8; ++g) {
                u16v8 v = *(const u16v8*)&Ys[(tok * N_QKV + 1024 + g * 64 + half * 32 + c * 8) ^ tsw];
                #pragma unroll
                for (int j = 0; j < 8; ++j) o[j] = fmaf(sc[g], bf2f(v[j]), o[j]);
            }
            u16v8 ov;
            #pragma unroll
            for (int j = 0; j < 8; ++j) ov[j] = f2bf(o[j]);
            const int zcol = (tok & 7) * 64 + half * 32 + c * 8;
            *(u16v8*)&Xs[(zrow * DIMC + zcol) ^ zsw] = ov;
        }
    }
    __syncthreads();

    // ---------- Phase 3: out GEMM. Per wave: 32 rows x 64 cols ----------
    const int n0o = wid * 64;
    f32v4 acc2[2][4] = {};
    #pragma unroll 1
    for (int kk = 0; kk < 16; ++kk) {
        bfv8 bf[4];
        #pragma unroll
        for (int nf = 0; nf < 4; ++nf)
            bf[nf] = *(const bfv8*)(Wo + (size_t)(n0o + nf * 16 + frow) * DIMC + kk * 32 + fcol);
        bfv8 af[2];
        #pragma unroll
        for (int m = 0; m < 2; ++m) {
            const int r = m * 16 + frow;
            af[m] = *(const bfv8*)&Xs[(r * DIMC + kk * 32 + fcol) ^ ((r & 7) << 3)];
        }
        #pragma unroll
        for (int m = 0; m < 2; ++m)
            #pragma unroll
            for (int nf = 0; nf < 4; ++nf)
                acc2[m][nf] = __builtin_amdgcn_mfma_f32_16x16x32_bf16(
                    af[m], bf[nf], acc2[m][nf], 0, 0, 0);
    }
    // epilogue: map local zrow -> global scrambled row, write fp32 + bias
    const int bidx = blk >> 7;     // batch (128 blocks per batch)
    const int nb   = blk & 127;
    #pragma unroll
    for (int nf = 0; nf < 4; ++nf) {
        const int col = n0o + nf * 16 + ecol;
        const float bv = out_b[col];
        #pragma unroll
        for (int m = 0; m < 2; ++m)
            #pragma unroll
            for (int r = 0; r < 4; ++r) {
                const int zrow = m * 16 + erow + r;
                const int srow = (zrow >> 2) * 512 + nb * 4 + (zrow & 3);
                Out[((size_t)bidx * SEQ + srow) * DIMC + col] = acc2[m][nf][r] + bv;
            }
    }
}

extern "C" void kernel_launch(void* const* d_in, const int* in_sizes, int n_in,
                              void* d_out, int out_size, void* d_ws, size_t ws_size,
                              hipStream_t stream) {
    const float* x     = (const float*)d_in[0];
    const float* qkv_w = (const float*)d_in[1];
    const float* qkv_b = (const float*)d_in[2];
    const float* out_w = (const float*)d_in[3];
    const float* out_b = (const float*)d_in[4];
    float* out = (float*)d_out;

    unsigned short* Wq = (unsigned short*)d_ws;                 // 1536x512 bf16
    unsigned short* Wo = Wq + (size_t)N_QKV * DIMC;             // 512x512 bf16

    cvt_f32_bf16<<<(N_QKV * DIMC / 8 + 255) / 256, 256, 0, stream>>>(qkv_w, Wq, N_QKV * DIMC / 8);
    cvt_f32_bf16<<<(DIMC * DIMC / 8 + 255) / 256, 256, 0, stream>>>(out_w, Wo, DIMC * DIMC / 8);

    fused_attn<<<M_TOK / 32, 512, 0, stream>>>(x, Wq, qkv_b, Wo, out_b, out);
}

// Round 5
// 85.715 us; speedup vs baseline: 1.7564x; 1.7564x over previous
//
#include <hip/hip_runtime.h>
#include <hip/hip_bf16.h>

#define DIMC 512
#define SEQ 4096
#define M_TOK 16384
#define N_QKV 1536

typedef __bf16 bfv8 __attribute__((ext_vector_type(8)));
typedef float f32v4 __attribute__((ext_vector_type(4)));
typedef unsigned short u16v8 __attribute__((ext_vector_type(8)));

static __device__ __forceinline__ float bf2f(unsigned short u) {
    union { unsigned int i; float f; } x; x.i = ((unsigned int)u) << 16; return x.f;
}
static __device__ __forceinline__ unsigned short f2bf(float f) {
    union { float f; unsigned int i; } x; x.f = f;
    unsigned int r = x.i + 0x7FFFu + ((x.i >> 16) & 1u);
    return (unsigned short)(r >> 16);
}

static __device__ __forceinline__ void gload_lds16(const void* g, void* s) {
    __builtin_amdgcn_global_load_lds(
        (const __attribute__((address_space(1))) unsigned int*)g,
        (__attribute__((address_space(3))) unsigned int*)s, 16, 0, 0);
}

// ---------------- merged fp32 -> bf16 conversion (x, qkv_w, out_w) ---------
#define NX8  (M_TOK * DIMC / 8)          // 1048576
#define NWQ8 (N_QKV * DIMC / 8)          // 98304
#define NWO8 (DIMC * DIMC / 8)           // 32768
__global__ __launch_bounds__(256) void cvt_all(
    const float* __restrict__ x,  const float* __restrict__ wq,
    const float* __restrict__ wo, unsigned short* __restrict__ xb,
    unsigned short* __restrict__ wqb, unsigned short* __restrict__ wob)
{
    int i = blockIdx.x * 256 + threadIdx.x;
    const float* src; unsigned short* dst; int off;
    if (i < NX8)             { src = x;  dst = xb;  off = i; }
    else if (i < NX8 + NWQ8) { src = wq; dst = wqb; off = i - NX8; }
    else                     { src = wo; dst = wob; off = i - NX8 - NWQ8; }
    const float4* p = (const float4*)src + (size_t)off * 2;
    float4 a = p[0], b = p[1];
    u16v8 o;
    o[0] = f2bf(a.x); o[1] = f2bf(a.y); o[2] = f2bf(a.z); o[3] = f2bf(a.w);
    o[4] = f2bf(b.x); o[5] = f2bf(b.y); o[6] = f2bf(b.z); o[7] = f2bf(b.w);
    *(u16v8*)(dst + (size_t)off * 8) = o;
}

// ---------- NT MFMA GEMM, 128x128 tile, BK=64, G4 swizzle both-sides -------
// C[M][N] = A[M][K]*B[N][K]^T + bias. 256 thr / 4 waves (2x2).
// LDS single-buffered: As/Bs [128][64] bf16, slot = e ^ (((e>>6)&7)<<3).
template<bool OUT_BF16>
__global__ __launch_bounds__(256) void gemm_nt_bk64(
    const unsigned short* __restrict__ A,  // [M][K] bf16
    const unsigned short* __restrict__ B,  // [N][K] bf16
    const float* __restrict__ bias,        // [N]
    void* __restrict__ Cout,
    int M, int N, int K)
{
    __shared__ __align__(16) unsigned short As[128 * 64];
    __shared__ __align__(16) unsigned short Bs[128 * 64];
    const int tid  = threadIdx.x;
    const int lane = tid & 63;
    const int wid  = tid >> 6;
    const int wm   = wid >> 1;
    const int wn   = wid & 1;
    const int m0 = blockIdx.x * 128;
    const int n0 = blockIdx.y * 128;
    const int frow = lane & 15;
    const int fcol = (lane >> 4) * 8;

    f32v4 acc[4][4] = {};

    // per-thread staging source addrs (4 rounds per matrix)
    const unsigned short* aSrc[4];
    const unsigned short* bSrc[4];
    #pragma unroll
    for (int s = 0; s < 4; ++s) {
        int p = s * 2048 + tid * 8;                 // linear LDS slot (elems)
        int row = p >> 6;
        int col = (p ^ (((p >> 6) & 7) << 3)) & 63; // inverse-swizzled source col
        aSrc[s] = A + (size_t)(m0 + row) * K + col;
        bSrc[s] = B + (size_t)(n0 + row) * K + col;
    }
    unsigned short* aDst = As + (tid >> 6) * 512;   // wave-uniform; +lane*8 by HW
    unsigned short* bDst = Bs + (tid >> 6) * 512;

    for (int kt = 0; kt < (K >> 6); ++kt) {
        #pragma unroll
        for (int s = 0; s < 4; ++s) {
            gload_lds16(aSrc[s] + kt * 64, aDst + s * 2048);
            gload_lds16(bSrc[s] + kt * 64, bDst + s * 2048);
        }
        __syncthreads();
        #pragma unroll
        for (int ks = 0; ks < 2; ++ks) {
            bfv8 af[4], bf[4];
            #pragma unroll
            for (int i = 0; i < 4; ++i) {
                const int r = wm * 64 + i * 16 + frow;
                const int e = r * 64 + ks * 32 + fcol;
                af[i] = *(const bfv8*)(As + (e ^ ((r & 7) << 3)));
            }
            #pragma unroll
            for (int j = 0; j < 4; ++j) {
                const int r = wn * 64 + j * 16 + frow;
                const int e = r * 64 + ks * 32 + fcol;
                bf[j] = *(const bfv8*)(Bs + (e ^ ((r & 7) << 3)));
            }
            #pragma unroll
            for (int i = 0; i < 4; ++i)
                #pragma unroll
                for (int j = 0; j < 4; ++j)
                    acc[i][j] = __builtin_amdgcn_mfma_f32_16x16x32_bf16(
                        af[i], bf[j], acc[i][j], 0, 0, 0);
        }
        __syncthreads();
    }

    // epilogue: D row=(lane>>4)*4+r, col=lane&15 (m89-verified, R2-proven)
    const int erow = (lane >> 4) * 4;
    const int ecol = lane & 15;
    #pragma unroll
    for (int j = 0; j < 4; ++j) {
        const int col = n0 + wn * 64 + j * 16 + ecol;
        const float bv = bias[col];
        #pragma unroll
        for (int i = 0; i < 4; ++i) {
            const int rbase = m0 + wm * 64 + i * 16 + erow;
            #pragma unroll
            for (int r = 0; r < 4; ++r) {
                const float v = acc[i][j][r] + bv;
                if constexpr (OUT_BF16)
                    ((unsigned short*)Cout)[(size_t)(rbase + r) * N + col] = f2bf(v);
                else
                    ((float*)Cout)[(size_t)(rbase + r) * N + col] = v;
            }
        }
    }
}

// ---------------- per-token 8x8 head-mix attention, LDS-free ----------------
// 16 lanes per token: lane16 = h*2 + half (half = 32-dim split).
// k/v reads are 8-lane broadcasts (merged by coalescer). 256 thr = 16 tokens.
// Writes Y2 scrambled: y[b][h*512 + (n>>3)][(n&7)*64 + d].
__global__ __launch_bounds__(256) void attn_mix2(
    const unsigned short* __restrict__ Y1, // [16384][1536] bf16
    unsigned short* __restrict__ Y2)       // [16384][512]  bf16 (scrambled)
{
    const int tid  = threadIdx.x;
    const int tok  = blockIdx.x * 16 + (tid >> 4);
    const int l16  = tid & 15;
    const int h    = l16 >> 1;
    const int half = l16 & 1;
    const unsigned short* qkv = Y1 + (size_t)tok * N_QKV;

    float qf[32];
    #pragma unroll
    for (int c = 0; c < 4; ++c) {
        u16v8 v = *(const u16v8*)(qkv + h * 64 + half * 32 + c * 8);
        #pragma unroll
        for (int j = 0; j < 8; ++j) qf[c * 8 + j] = bf2f(v[j]);
    }
    float sc[8];
    #pragma unroll
    for (int g = 0; g < 8; ++g) {
        const unsigned short* kp = qkv + DIMC + g * 64 + half * 32;
        float a = 0.f;
        #pragma unroll
        for (int c = 0; c < 4; ++c) {
            u16v8 v = *(const u16v8*)(kp + c * 8);
            #pragma unroll
            for (int j = 0; j < 8; ++j) a = fmaf(qf[c * 8 + j], bf2f(v[j]), a);
        }
        a += __shfl_xor(a, 1);       // combine the two 32-dim halves
        sc[g] = a * 0.125f;
    }
    float mx = sc[0];
    #pragma unroll
    for (int g = 1; g < 8; ++g) mx = fmaxf(mx, sc[g]);
    float sum = 0.f;
    #pragma unroll
    for (int g = 0; g < 8; ++g) { sc[g] = __expf(sc[g] - mx); sum += sc[g]; }
    const float inv = 1.f / sum;
    #pragma unroll
    for (int g = 0; g < 8; ++g) sc[g] *= inv;

    float o[32] = {};
    #pragma unroll
    for (int g = 0; g < 8; ++g) {
        const unsigned short* vp = qkv + 2 * DIMC + g * 64 + half * 32;
        #pragma unroll
        for (int c = 0; c < 4; ++c) {
            u16v8 v = *(const u16v8*)(vp + c * 8);
            #pragma unroll
            for (int j = 0; j < 8; ++j) o[c * 8 + j] = fmaf(sc[g], bf2f(v[j]), o[c * 8 + j]);
        }
    }
    const int n = tok & (SEQ - 1);
    const int b = tok >> 12;
    const size_t drow = (size_t)b * SEQ + h * 512 + (n >> 3);
    unsigned short* dst = Y2 + drow * DIMC + ((n & 7) << 6) + half * 32;
    #pragma unroll
    for (int c = 0; c < 4; ++c) {
        u16v8 ov;
        #pragma unroll
        for (int j = 0; j < 8; ++j) ov[j] = f2bf(o[c * 8 + j]);
        *(u16v8*)(dst + c * 8) = ov;
    }
}

extern "C" void kernel_launch(void* const* d_in, const int* in_sizes, int n_in,
                              void* d_out, int out_size, void* d_ws, size_t ws_size,
                              hipStream_t stream) {
    const float* x     = (const float*)d_in[0];
    const float* qkv_w = (const float*)d_in[1];
    const float* qkv_b = (const float*)d_in[2];
    const float* out_w = (const float*)d_in[3];
    const float* out_b = (const float*)d_in[4];
    float* out = (float*)d_out;

    unsigned short* Y1 = (unsigned short*)d_ws;            // 50.3 MB
    unsigned short* Xb = Y1 + (size_t)M_TOK * N_QKV;       // 16.8 MB
    unsigned short* Y2 = Xb;   // overlay: Xb dead before attn_mix2 writes Y2
    unsigned short* Wq = Xb + (size_t)M_TOK * DIMC;
    unsigned short* Wo = Wq + (size_t)N_QKV * DIMC;

    cvt_all<<<(NX8 + NWQ8 + NWO8) / 256, 256, 0, stream>>>(x, qkv_w, out_w, Xb, Wq, Wo);

    gemm_nt_bk64<true><<<dim3(M_TOK / 128, N_QKV / 128), 256, 0, stream>>>(
        Xb, Wq, qkv_b, Y1, M_TOK, N_QKV, DIMC);

    attn_mix2<<<M_TOK / 16, 256, 0, stream>>>(Y1, Y2);

    gemm_nt_bk64<false><<<dim3(M_TOK / 128, DIMC / 128), 256, 0, stream>>>(
        Y2, Wo, out_b, out, M_TOK, DIMC, DIMC);
}

// Round 6
// 83.982 us; speedup vs baseline: 1.7927x; 1.0206x over previous
//
#include <hip/hip_runtime.h>
#include <hip/hip_bf16.h>

#define DIMC 512
#define SEQ 4096
#define M_TOK 16384
#define N_QKV 1536

typedef __bf16 bfv8 __attribute__((ext_vector_type(8)));
typedef float f32v4 __attribute__((ext_vector_type(4)));
typedef unsigned short u16v8 __attribute__((ext_vector_type(8)));

static __device__ __forceinline__ float bf2f(unsigned short u) {
    union { unsigned int i; float f; } x; x.i = ((unsigned int)u) << 16; return x.f;
}
static __device__ __forceinline__ unsigned short f2bf(float f) {
    union { float f; unsigned int i; } x; x.f = f;
    unsigned int r = x.i + 0x7FFFu + ((x.i >> 16) & 1u);
    return (unsigned short)(r >> 16);
}

static __device__ __forceinline__ void gload_lds16(const void* g, void* s) {
    __builtin_amdgcn_global_load_lds(
        (const __attribute__((address_space(1))) unsigned int*)g,
        (__attribute__((address_space(3))) unsigned int*)s, 16, 0, 0);
}

// ---------------- merged fp32 -> bf16 conversion (x, qkv_w, out_w) ---------
#define NX8  (M_TOK * DIMC / 8)          // 1048576
#define NWQ8 (N_QKV * DIMC / 8)          // 98304
#define NWO8 (DIMC * DIMC / 8)           // 32768
__global__ __launch_bounds__(256) void cvt_all(
    const float* __restrict__ x,  const float* __restrict__ wq,
    const float* __restrict__ wo, unsigned short* __restrict__ xb,
    unsigned short* __restrict__ wqb, unsigned short* __restrict__ wob)
{
    int i = blockIdx.x * 256 + threadIdx.x;
    const float* src; unsigned short* dst; int off;
    if (i < NX8)             { src = x;  dst = xb;  off = i; }
    else if (i < NX8 + NWQ8) { src = wq; dst = wqb; off = i - NX8; }
    else                     { src = wo; dst = wob; off = i - NX8 - NWQ8; }
    const float4* p = (const float4*)src + (size_t)off * 2;
    float4 a = p[0], b = p[1];
    u16v8 o;
    o[0] = f2bf(a.x); o[1] = f2bf(a.y); o[2] = f2bf(a.z); o[3] = f2bf(a.w);
    o[4] = f2bf(b.x); o[5] = f2bf(b.y); o[6] = f2bf(b.z); o[7] = f2bf(b.w);
    *(u16v8*)(dst + (size_t)off * 8) = o;
}

// ---- NT MFMA GEMM, 128x128 tile, BK=32, T3-minimum 2-phase double-buffer --
// C[M][N] = A[M][K]*B[N][K]^T + bias. 256 thr / 4 waves (2x2).
// LDS: As/Bs [2][128][32] bf16 = 32KB total (same as R5 -> occupancy kept).
// Swizzle: e ^= ((row>>1)&3)<<3  -> 16 frag rows hit 8 distinct bank-slots
// (2-way = free, m136). Inverse-swizzled global source (rule 21).
// Schedule (T3-minimum): STAGE(t+1) issued BEFORE compute(t); one
// __syncthreads (vmcnt0+lgkm0+barrier) per K-tile at the bottom.
template<bool OUT_BF16>
__global__ __launch_bounds__(256) void gemm_nt_2ph(
    const unsigned short* __restrict__ A,  // [M][K] bf16
    const unsigned short* __restrict__ B,  // [N][K] bf16
    const float* __restrict__ bias,        // [N]
    void* __restrict__ Cout,
    int M, int N, int K)
{
    __shared__ __align__(16) unsigned short As[2][128 * 32];
    __shared__ __align__(16) unsigned short Bs[2][128 * 32];
    const int tid  = threadIdx.x;
    const int lane = tid & 63;
    const int wid  = tid >> 6;
    const int wm   = wid >> 1;
    const int wn   = wid & 1;
    const int m0 = blockIdx.x * 128;
    const int n0 = blockIdx.y * 128;
    const int frow = lane & 15;
    const int fcol = (lane >> 4) * 8;
    const int NT = K >> 5;                 // 16 K-tiles

    f32v4 acc[4][4] = {};

    // staging: per matrix per tile, 2 chunks/thread. chunk c = s*256+tid,
    // linear LDS elem p = c*8, row = p>>5. Source col inverse-swizzled.
    const unsigned short* aSrc[2];
    const unsigned short* bSrc[2];
    #pragma unroll
    for (int s = 0; s < 2; ++s) {
        const int p   = (s * 256 + tid) * 8;
        const int row = p >> 5;
        const int col = (p & 31) ^ (((row >> 1) & 3) << 3);
        aSrc[s] = A + (size_t)(m0 + row) * K + col;
        bSrc[s] = B + (size_t)(n0 + row) * K + col;
    }
    // wave-uniform LDS dest bases (HW adds lane*16B)
    const int dstOff[2] = { wid * 512, 2048 + wid * 512 };

#define STAGE(kt, buf)                                                         \
    {                                                                          \
        _Pragma("unroll") for (int s = 0; s < 2; ++s) {                        \
            gload_lds16(aSrc[s] + (kt) * 32, &As[buf][dstOff[s]]);             \
            gload_lds16(bSrc[s] + (kt) * 32, &Bs[buf][dstOff[s]]);             \
        }                                                                      \
    }

    STAGE(0, 0)
    __syncthreads();

    for (int t = 0; t < NT; ++t) {
        const int p = t & 1;
        if (t + 1 < NT) STAGE(t + 1, p ^ 1)
        bfv8 af[4], bf[4];
        #pragma unroll
        for (int i = 0; i < 4; ++i) {
            const int r = wm * 64 + i * 16 + frow;
            af[i] = *(const bfv8*)(&As[p][r * 32 + (fcol ^ (((r >> 1) & 3) << 3))]);
        }
        #pragma unroll
        for (int j = 0; j < 4; ++j) {
            const int r = wn * 64 + j * 16 + frow;
            bf[j] = *(const bfv8*)(&Bs[p][r * 32 + (fcol ^ (((r >> 1) & 3) << 3))]);
        }
        #pragma unroll
        for (int i = 0; i < 4; ++i)
            #pragma unroll
            for (int j = 0; j < 4; ++j)
                acc[i][j] = __builtin_amdgcn_mfma_f32_16x16x32_bf16(
                    af[i], bf[j], acc[i][j], 0, 0, 0);
        __syncthreads();   // vmcnt(0)+lgkm(0)+barrier: t+1 staged, bufs safe
    }
#undef STAGE

    // epilogue: D row=(lane>>4)*4+r, col=lane&15 (m89-verified, R2/R5-proven)
    const int erow = (lane >> 4) * 4;
    const int ecol = lane & 15;
    #pragma unroll
    for (int j = 0; j < 4; ++j) {
        const int col = n0 + wn * 64 + j * 16 + ecol;
        const float bv = bias[col];
        #pragma unroll
        for (int i = 0; i < 4; ++i) {
            const int rbase = m0 + wm * 64 + i * 16 + erow;
            #pragma unroll
            for (int r = 0; r < 4; ++r) {
                const float v = acc[i][j][r] + bv;
                if constexpr (OUT_BF16)
                    ((unsigned short*)Cout)[(size_t)(rbase + r) * N + col] = f2bf(v);
                else
                    ((float*)Cout)[(size_t)(rbase + r) * N + col] = v;
            }
        }
    }
}

// ---------------- per-token 8x8 head-mix attention, LDS-free ----------------
// 16 lanes per token: lane16 = h*2 + half (half = 32-dim split).
// Writes Y2 scrambled: y[b][h*512 + (n>>3)][(n&7)*64 + d].
__global__ __launch_bounds__(256) void attn_mix2(
    const unsigned short* __restrict__ Y1, // [16384][1536] bf16
    unsigned short* __restrict__ Y2)       // [16384][512]  bf16 (scrambled)
{
    const int tid  = threadIdx.x;
    const int tok  = blockIdx.x * 16 + (tid >> 4);
    const int l16  = tid & 15;
    const int h    = l16 >> 1;
    const int half = l16 & 1;
    const unsigned short* qkv = Y1 + (size_t)tok * N_QKV;

    float qf[32];
    #pragma unroll
    for (int c = 0; c < 4; ++c) {
        u16v8 v = *(const u16v8*)(qkv + h * 64 + half * 32 + c * 8);
        #pragma unroll
        for (int j = 0; j < 8; ++j) qf[c * 8 + j] = bf2f(v[j]);
    }
    float sc[8];
    #pragma unroll
    for (int g = 0; g < 8; ++g) {
        const unsigned short* kp = qkv + DIMC + g * 64 + half * 32;
        float a = 0.f;
        #pragma unroll
        for (int c = 0; c < 4; ++c) {
            u16v8 v = *(const u16v8*)(kp + c * 8);
            #pragma unroll
            for (int j = 0; j < 8; ++j) a = fmaf(qf[c * 8 + j], bf2f(v[j]), a);
        }
        a += __shfl_xor(a, 1);       // combine the two 32-dim halves
        sc[g] = a * 0.125f;
    }
    float mx = sc[0];
    #pragma unroll
    for (int g = 1; g < 8; ++g) mx = fmaxf(mx, sc[g]);
    float sum = 0.f;
    #pragma unroll
    for (int g = 0; g < 8; ++g) { sc[g] = __expf(sc[g] - mx); sum += sc[g]; }
    const float inv = 1.f / sum;
    #pragma unroll
    for (int g = 0; g < 8; ++g) sc[g] *= inv;

    float o[32] = {};
    #pragma unroll
    for (int g = 0; g < 8; ++g) {
        const unsigned short* vp = qkv + 2 * DIMC + g * 64 + half * 32;
        #pragma unroll
        for (int c = 0; c < 4; ++c) {
            u16v8 v = *(const u16v8*)(vp + c * 8);
            #pragma unroll
            for (int j = 0; j < 8; ++j) o[c * 8 + j] = fmaf(sc[g], bf2f(v[j]), o[c * 8 + j]);
        }
    }
    const int n = tok & (SEQ - 1);
    const int b = tok >> 12;
    const size_t drow = (size_t)b * SEQ + h * 512 + (n >> 3);
    unsigned short* dst = Y2 + drow * DIMC + ((n & 7) << 6) + half * 32;
    #pragma unroll
    for (int c = 0; c < 4; ++c) {
        u16v8 ov;
        #pragma unroll
        for (int j = 0; j < 8; ++j) ov[j] = f2bf(o[c * 8 + j]);
        *(u16v8*)(dst + c * 8) = ov;
    }
}

extern "C" void kernel_launch(void* const* d_in, const int* in_sizes, int n_in,
                              void* d_out, int out_size, void* d_ws, size_t ws_size,
                              hipStream_t stream) {
    const float* x     = (const float*)d_in[0];
    const float* qkv_w = (const float*)d_in[1];
    const float* qkv_b = (const float*)d_in[2];
    const float* out_w = (const float*)d_in[3];
    const float* out_b = (const float*)d_in[4];
    float* out = (float*)d_out;

    unsigned short* Y1 = (unsigned short*)d_ws;            // 50.3 MB
    unsigned short* Xb = Y1 + (size_t)M_TOK * N_QKV;       // 16.8 MB
    unsigned short* Y2 = Xb;   // overlay: Xb dead before attn_mix2 writes Y2
    unsigned short* Wq = Xb + (size_t)M_TOK * DIMC;
    unsigned short* Wo = Wq + (size_t)N_QKV * DIMC;

    cvt_all<<<(NX8 + NWQ8 + NWO8) / 256, 256, 0, stream>>>(x, qkv_w, out_w, Xb, Wq, Wo);

    gemm_nt_2ph<true><<<dim3(M_TOK / 128, N_QKV / 128), 256, 0, stream>>>(
        Xb, Wq, qkv_b, Y1, M_TOK, N_QKV, DIMC);

    attn_mix2<<<M_TOK / 16, 256, 0, stream>>>(Y1, Y2);

    gemm_nt_2ph<false><<<dim3(M_TOK / 128, DIMC / 128), 256, 0, stream>>>(
        Y2, Wo, out_b, out, M_TOK, DIMC, DIMC);
}

// Round 7
// 81.978 us; speedup vs baseline: 1.8365x; 1.0244x over previous
//
#include <hip/hip_runtime.h>
#include <hip/hip_bf16.h>

#define DIMC 512
#define SEQ 4096
#define M_TOK 16384
#define N_QKV 1536

typedef __bf16 bfv8 __attribute__((ext_vector_type(8)));
typedef float f32v4 __attribute__((ext_vector_type(4)));
typedef unsigned short u16v8 __attribute__((ext_vector_type(8)));

static __device__ __forceinline__ float bf2f(unsigned short u) {
    union { unsigned int i; float f; } x; x.i = ((unsigned int)u) << 16; return x.f;
}
static __device__ __forceinline__ unsigned short f2bf(float f) {
    union { float f; unsigned int i; } x; x.f = f;
    unsigned int r = x.i + 0x7FFFu + ((x.i >> 16) & 1u);
    return (unsigned short)(r >> 16);
}

static __device__ __forceinline__ void gload_lds16(const void* g, void* s) {
    __builtin_amdgcn_global_load_lds(
        (const __attribute__((address_space(1))) unsigned int*)g,
        (__attribute__((address_space(3))) unsigned int*)s, 16, 0, 0);
}

// ---------------- merged fp32 -> bf16 conversion (x, qkv_w, out_w) ---------
#define NX8  (M_TOK * DIMC / 8)          // 1048576
#define NWQ8 (N_QKV * DIMC / 8)          // 98304
#define NWO8 (DIMC * DIMC / 8)           // 32768
__global__ __launch_bounds__(256) void cvt_all(
    const float* __restrict__ x,  const float* __restrict__ wq,
    const float* __restrict__ wo, unsigned short* __restrict__ xb,
    unsigned short* __restrict__ wqb, unsigned short* __restrict__ wob)
{
    int i = blockIdx.x * 256 + threadIdx.x;
    const float* src; unsigned short* dst; int off;
    if (i < NX8)             { src = x;  dst = xb;  off = i; }
    else if (i < NX8 + NWQ8) { src = wq; dst = wqb; off = i - NX8; }
    else                     { src = wo; dst = wob; off = i - NX8 - NWQ8; }
    const float4* p = (const float4*)src + (size_t)off * 2;
    float4 a = p[0], b = p[1];
    u16v8 o;
    o[0] = f2bf(a.x); o[1] = f2bf(a.y); o[2] = f2bf(a.z); o[3] = f2bf(a.w);
    o[4] = f2bf(b.x); o[5] = f2bf(b.y); o[6] = f2bf(b.z); o[7] = f2bf(b.w);
    *(u16v8*)(dst + (size_t)off * 8) = o;
}

// ---- NT MFMA GEMM, 128x128 tile, BK=32 2-phase dbuf, 512 thr / 8 waves ----
// C[M][N] = A[M][K]*B[N][K]^T + bias. Wave grid 2x4, per-wave 64x32 tile.
// Rationale (R6 post-mortem): 256-thr blocks left only ~8 waves/CU resident;
// 512-thr blocks make all 3 blocks/CU co-resident -> 24 waves/CU hiding.
// LDS: As/Bs [2][128][32] bf16 = 32KB. Swizzle e ^= ((row>>1)&3)<<3 both-sides
// (rule 21; SQ_LDS_BANK_CONFLICT == 0 measured in R6).
template<bool OUT_BF16>
__global__ __launch_bounds__(512) void gemm_nt_2ph(
    const unsigned short* __restrict__ A,  // [M][K] bf16
    const unsigned short* __restrict__ B,  // [N][K] bf16
    const float* __restrict__ bias,        // [N]
    void* __restrict__ Cout,
    int M, int N, int K)
{
    __shared__ __align__(16) unsigned short As[2][128 * 32];
    __shared__ __align__(16) unsigned short Bs[2][128 * 32];
    const int tid  = threadIdx.x;
    const int lane = tid & 63;
    const int wid  = tid >> 6;       // 0..7
    const int wm   = wid >> 2;       // 0..1 -> rows [wm*64,+64)
    const int wn   = wid & 3;        // 0..3 -> cols [wn*32,+32)
    const int m0 = blockIdx.x * 128;
    const int n0 = blockIdx.y * 128;
    const int frow = lane & 15;
    const int fcol = (lane >> 4) * 8;
    const int NT = K >> 5;           // 16 K-tiles

    f32v4 acc[4][2] = {};

    // staging: 512 thr x 8 elems = full 128x32 tile per matrix, 1 chunk each.
    // p = tid*8; row = tid>>2; source col inverse-swizzled.
    const int srow = tid >> 2;
    const int scol = ((tid & 3) * 8) ^ (((srow >> 1) & 3) << 3);
    const unsigned short* aSrc = A + (size_t)(m0 + srow) * K + scol;
    const unsigned short* bSrc = B + (size_t)(n0 + srow) * K + scol;
    const int dstOff = wid * 512;    // wave-uniform; HW adds lane*16B

#define STAGE(kt, buf)                                                         \
    {                                                                          \
        gload_lds16(aSrc + (kt) * 32, &As[buf][dstOff]);                       \
        gload_lds16(bSrc + (kt) * 32, &Bs[buf][dstOff]);                       \
    }

    STAGE(0, 0)
    __syncthreads();

    for (int t = 0; t < NT; ++t) {
        const int p = t & 1;
        if (t + 1 < NT) STAGE(t + 1, p ^ 1)
        bfv8 af[4], bf[2];
        #pragma unroll
        for (int i = 0; i < 4; ++i) {
            const int r = wm * 64 + i * 16 + frow;
            af[i] = *(const bfv8*)(&As[p][r * 32 + (fcol ^ (((r >> 1) & 3) << 3))]);
        }
        #pragma unroll
        for (int j = 0; j < 2; ++j) {
            const int r = wn * 32 + j * 16 + frow;
            bf[j] = *(const bfv8*)(&Bs[p][r * 32 + (fcol ^ (((r >> 1) & 3) << 3))]);
        }
        #pragma unroll
        for (int i = 0; i < 4; ++i)
            #pragma unroll
            for (int j = 0; j < 2; ++j)
                acc[i][j] = __builtin_amdgcn_mfma_f32_16x16x32_bf16(
                    af[i], bf[j], acc[i][j], 0, 0, 0);
        __syncthreads();   // t+1 staged & drained; bufs safe to swap
    }
#undef STAGE

    // epilogue: D row=(lane>>4)*4+r, col=lane&15 (m89-verified, R2/R5-proven)
    const int erow = (lane >> 4) * 4;
    const int ecol = lane & 15;
    #pragma unroll
    for (int j = 0; j < 2; ++j) {
        const int col = n0 + wn * 32 + j * 16 + ecol;
        const float bv = bias[col];
        #pragma unroll
        for (int i = 0; i < 4; ++i) {
            const int rbase = m0 + wm * 64 + i * 16 + erow;
            #pragma unroll
            for (int r = 0; r < 4; ++r) {
                const float v = acc[i][j][r] + bv;
                if constexpr (OUT_BF16)
                    ((unsigned short*)Cout)[(size_t)(rbase + r) * N + col] = f2bf(v);
                else
                    ((float*)Cout)[(size_t)(rbase + r) * N + col] = v;
            }
        }
    }
}

// ---------------- per-token 8x8 head-mix attention, LDS-free ----------------
// 16 lanes per token: lane16 = h*2 + half (half = 32-dim split).
// Writes Y2 scrambled: y[b][h*512 + (n>>3)][(n&7)*64 + d].
__global__ __launch_bounds__(256) void attn_mix2(
    const unsigned short* __restrict__ Y1, // [16384][1536] bf16
    unsigned short* __restrict__ Y2)       // [16384][512]  bf16 (scrambled)
{
    const int tid  = threadIdx.x;
    const int tok  = blockIdx.x * 16 + (tid >> 4);
    const int l16  = tid & 15;
    const int h    = l16 >> 1;
    const int half = l16 & 1;
    const unsigned short* qkv = Y1 + (size_t)tok * N_QKV;

    float qf[32];
    #pragma unroll
    for (int c = 0; c < 4; ++c) {
        u16v8 v = *(const u16v8*)(qkv + h * 64 + half * 32 + c * 8);
        #pragma unroll
        for (int j = 0; j < 8; ++j) qf[c * 8 + j] = bf2f(v[j]);
    }
    float sc[8];
    #pragma unroll
    for (int g = 0; g < 8; ++g) {
        const unsigned short* kp = qkv + DIMC + g * 64 + half * 32;
        float a = 0.f;
        #pragma unroll
        for (int c = 0; c < 4; ++c) {
            u16v8 v = *(const u16v8*)(kp + c * 8);
            #pragma unroll
            for (int j = 0; j < 8; ++j) a = fmaf(qf[c * 8 + j], bf2f(v[j]), a);
        }
        a += __shfl_xor(a, 1);       // combine the two 32-dim halves
        sc[g] = a * 0.125f;
    }
    float mx = sc[0];
    #pragma unroll
    for (int g = 1; g < 8; ++g) mx = fmaxf(mx, sc[g]);
    float sum = 0.f;
    #pragma unroll
    for (int g = 0; g < 8; ++g) { sc[g] = __expf(sc[g] - mx); sum += sc[g]; }
    const float inv = 1.f / sum;
    #pragma unroll
    for (int g = 0; g < 8; ++g) sc[g] *= inv;

    float o[32] = {};
    #pragma unroll
    for (int g = 0; g < 8; ++g) {
        const unsigned short* vp = qkv + 2 * DIMC + g * 64 + half * 32;
        #pragma unroll
        for (int c = 0; c < 4; ++c) {
            u16v8 v = *(const u16v8*)(vp + c * 8);
            #pragma unroll
            for (int j = 0; j < 8; ++j) o[c * 8 + j] = fmaf(sc[g], bf2f(v[j]), o[c * 8 + j]);
        }
    }
    const int n = tok & (SEQ - 1);
    const int b = tok >> 12;
    const size_t drow = (size_t)b * SEQ + h * 512 + (n >> 3);
    unsigned short* dst = Y2 + drow * DIMC + ((n & 7) << 6) + half * 32;
    #pragma unroll
    for (int c = 0; c < 4; ++c) {
        u16v8 ov;
        #pragma unroll
        for (int j = 0; j < 8; ++j) ov[j] = f2bf(o[c * 8 + j]);
        *(u16v8*)(dst + c * 8) = ov;
    }
}

extern "C" void kernel_launch(void* const* d_in, const int* in_sizes, int n_in,
                              void* d_out, int out_size, void* d_ws, size_t ws_size,
                              hipStream_t stream) {
    const float* x     = (const float*)d_in[0];
    const float* qkv_w = (const float*)d_in[1];
    const float* qkv_b = (const float*)d_in[2];
    const float* out_w = (const float*)d_in[3];
    const float* out_b = (const float*)d_in[4];
    float* out = (float*)d_out;

    unsigned short* Y1 = (unsigned short*)d_ws;            // 50.3 MB
    unsigned short* Xb = Y1 + (size_t)M_TOK * N_QKV;       // 16.8 MB
    unsigned short* Y2 = Xb;   // overlay: Xb dead before attn_mix2 writes Y2
    unsigned short* Wq = Xb + (size_t)M_TOK * DIMC;
    unsigned short* Wo = Wq + (size_t)N_QKV * DIMC;

    cvt_all<<<(NX8 + NWQ8 + NWO8) / 256, 256, 0, stream>>>(x, qkv_w, out_w, Xb, Wq, Wo);

    gemm_nt_2ph<true><<<dim3(M_TOK / 128, N_QKV / 128), 512, 0, stream>>>(
        Xb, Wq, qkv_b, Y1, M_TOK, N_QKV, DIMC);

    attn_mix2<<<M_TOK / 16, 256, 0, stream>>>(Y1, Y2);

    gemm_nt_2ph<false><<<dim3(M_TOK / 128, DIMC / 128), 512, 0, stream>>>(
        Y2, Wo, out_b, out, M_TOK, DIMC, DIMC);
}

// Round 8
// 81.146 us; speedup vs baseline: 1.8554x; 1.0103x over previous
//
#include <hip/hip_runtime.h>
#include <hip/hip_bf16.h>

#define DIMC 512
#define SEQ 4096
#define M_TOK 16384
#define N_QKV 1536

typedef __bf16 bfv8 __attribute__((ext_vector_type(8)));
typedef float f32v4 __attribute__((ext_vector_type(4)));
typedef unsigned short u16v8 __attribute__((ext_vector_type(8)));

#define VMCNT(n) asm volatile("s_waitcnt vmcnt(" #n ")" ::: "memory")
#define LGKM0()  asm volatile("s_waitcnt lgkmcnt(0)" ::: "memory")

static __device__ __forceinline__ float bf2f(unsigned short u) {
    union { unsigned int i; float f; } x; x.i = ((unsigned int)u) << 16; return x.f;
}
static __device__ __forceinline__ unsigned short f2bf(float f) {
    union { float f; unsigned int i; } x; x.f = f;
    unsigned int r = x.i + 0x7FFFu + ((x.i >> 16) & 1u);
    return (unsigned short)(r >> 16);
}

static __device__ __forceinline__ void gload_lds16(const void* g, void* s) {
    __builtin_amdgcn_global_load_lds(
        (const __attribute__((address_space(1))) unsigned int*)g,
        (__attribute__((address_space(3))) unsigned int*)s, 16, 0, 0);
}

// ---------------- merged fp32 -> bf16 conversion (x, qkv_w, out_w) ---------
#define NX8  (M_TOK * DIMC / 8)          // 1048576
#define NWQ8 (N_QKV * DIMC / 8)          // 98304
#define NWO8 (DIMC * DIMC / 8)           // 32768
__global__ __launch_bounds__(256) void cvt_all(
    const float* __restrict__ x,  const float* __restrict__ wq,
    const float* __restrict__ wo, unsigned short* __restrict__ xb,
    unsigned short* __restrict__ wqb, unsigned short* __restrict__ wob)
{
    int i = blockIdx.x * 256 + threadIdx.x;
    const float* src; unsigned short* dst; int off;
    if (i < NX8)             { src = x;  dst = xb;  off = i; }
    else if (i < NX8 + NWQ8) { src = wq; dst = wqb; off = i - NX8; }
    else                     { src = wo; dst = wob; off = i - NX8 - NWQ8; }
    const float4* p = (const float4*)src + (size_t)off * 2;
    float4 a = p[0], b = p[1];
    u16v8 o;
    o[0] = f2bf(a.x); o[1] = f2bf(a.y); o[2] = f2bf(a.z); o[3] = f2bf(a.w);
    o[4] = f2bf(b.x); o[5] = f2bf(b.y); o[6] = f2bf(b.z); o[7] = f2bf(b.w);
    *(u16v8*)(dst + (size_t)off * 8) = o;
}

// ---- NT MFMA GEMM, 128x256 block, BK=32, RING-3 LDS + counted vmcnt -------
// C[M][N] = A[M][K]*B[N][K]^T + bias. 512 thr / 8 waves (2Mx4N), 64x64/wave.
// R7 post-mortem: the vmcnt(0) drain inside __syncthreads was the binder
// (prefetch distance ~0.5 iter). Here: 3-deep LDS ring, STAGE(t+2) issued at
// iter t, ONE raw s_barrier per K-tile, vmcnt(3) counted (never 0 until tail).
// Race-freedom: readers of slot s at iter t-1 are lgkm-drained before
// barrier(t-1); STAGE(t+2)->slot s issues after barrier(t-1).
// Swizzle e ^= ((row>>1)&3)<<3 both-sides (0 conflicts measured R6/R7).
template<bool OUT_BF16>
__global__ __launch_bounds__(512) void gemm_nt_r3(
    const unsigned short* __restrict__ A,  // [M][K] bf16
    const unsigned short* __restrict__ B,  // [N][K] bf16
    const float* __restrict__ bias,        // [N]
    void* __restrict__ Cout,
    int M, int N, int K)
{
    __shared__ __align__(16) unsigned short As[3][128 * 32];   // 24KB
    __shared__ __align__(16) unsigned short Bs[3][256 * 32];   // 48KB
    const int tid  = threadIdx.x;
    const int lane = tid & 63;
    const int wid  = tid >> 6;       // 0..7
    const int wm   = wid >> 2;       // 0..1 -> rows [wm*64,+64)
    const int wn   = wid & 3;        // 0..3 -> cols [wn*64,+64)
    const int m0 = blockIdx.x * 128;
    const int n0 = blockIdx.y * 256;
    const int frow = lane & 15;
    const int fcol = (lane >> 4) * 8;
    const int NT = K >> 5;           // 16 K-tiles

    f32v4 acc[4][4] = {};

    // staging addresses (inverse-swizzled global source, rule 21)
    // A: 512 chunks (1/thread): row=tid>>2, col=(tid&3)*8 ^ swz(row)
    // B: 1024 chunks (2/thread): round r, row=r*128+(tid>>2)
    const int arow = tid >> 2;
    const int acol = ((tid & 3) * 8) ^ (((arow >> 1) & 3) << 3);
    const unsigned short* aSrc = A + (size_t)(m0 + arow) * K + acol;
    const unsigned short* bSrc[2];
    #pragma unroll
    for (int r = 0; r < 2; ++r) {
        const int brow = r * 128 + (tid >> 2);
        const int bcol = ((tid & 3) * 8) ^ (((brow >> 1) & 3) << 3);
        bSrc[r] = B + (size_t)(n0 + brow) * K + bcol;
    }
    const int aDst = wid * 512;            // wave-uniform (+lane*16B by HW)

#define STAGE(kt, slot)                                                        \
    {                                                                          \
        gload_lds16(aSrc + (kt) * 32, &As[slot][aDst]);                        \
        gload_lds16(bSrc[0] + (kt) * 32, &Bs[slot][aDst]);                     \
        gload_lds16(bSrc[1] + (kt) * 32, &Bs[slot][4096 + aDst]);              \
    }

    STAGE(0, 0)
    STAGE(1, 1)
    VMCNT(3);                      // tile-0 landed (only tile-1's 3 remain)
    __builtin_amdgcn_s_barrier();

    for (int t = 0; t < NT; ++t) {
        const int slot = t % 3;
        bfv8 af[4], bf[4];
        #pragma unroll
        for (int i = 0; i < 4; ++i) {
            const int r = wm * 64 + i * 16 + frow;
            af[i] = *(const bfv8*)(&As[slot][r * 32 + (fcol ^ (((r >> 1) & 3) << 3))]);
        }
        #pragma unroll
        for (int j = 0; j < 4; ++j) {
            const int r = wn * 64 + j * 16 + frow;
            bf[j] = *(const bfv8*)(&Bs[slot][r * 32 + (fcol ^ (((r >> 1) & 3) << 3))]);
        }
        if (t + 2 < NT) {
            const int ws = (t + 2) % 3;
            STAGE(t + 2, ws)
        }
        LGKM0(); __builtin_amdgcn_sched_barrier(0);
        #pragma unroll
        for (int i = 0; i < 4; ++i)
            #pragma unroll
            for (int j = 0; j < 4; ++j)
                acc[i][j] = __builtin_amdgcn_mfma_f32_16x16x32_bf16(
                    af[i], bf[j], acc[i][j], 0, 0, 0);
        if (t + 2 < NT) { VMCNT(3); } else { VMCNT(0); }
        __builtin_amdgcn_s_barrier();
    }
#undef STAGE

    // epilogue: D row=(lane>>4)*4+r, col=lane&15 (m89-verified, R2..R7-proven)
    const int erow = (lane >> 4) * 4;
    const int ecol = lane & 15;
    #pragma unroll
    for (int j = 0; j < 4; ++j) {
        const int col = n0 + wn * 64 + j * 16 + ecol;
        const float bv = bias[col];
        #pragma unroll
        for (int i = 0; i < 4; ++i) {
            const int rbase = m0 + wm * 64 + i * 16 + erow;
            #pragma unroll
            for (int r = 0; r < 4; ++r) {
                const float v = acc[i][j][r] + bv;
                if constexpr (OUT_BF16)
                    ((unsigned short*)Cout)[(size_t)(rbase + r) * N + col] = f2bf(v);
                else
                    ((float*)Cout)[(size_t)(rbase + r) * N + col] = v;
            }
        }
    }
}

// ---------------- per-token 8x8 head-mix attention, LDS-free ----------------
// 16 lanes per token: lane16 = h*2 + half (half = 32-dim split).
// Writes Y2 scrambled: y[b][h*512 + (n>>3)][(n&7)*64 + d].
__global__ __launch_bounds__(256) void attn_mix2(
    const unsigned short* __restrict__ Y1, // [16384][1536] bf16
    unsigned short* __restrict__ Y2)       // [16384][512]  bf16 (scrambled)
{
    const int tid  = threadIdx.x;
    const int tok  = blockIdx.x * 16 + (tid >> 4);
    const int l16  = tid & 15;
    const int h    = l16 >> 1;
    const int half = l16 & 1;
    const unsigned short* qkv = Y1 + (size_t)tok * N_QKV;

    float qf[32];
    #pragma unroll
    for (int c = 0; c < 4; ++c) {
        u16v8 v = *(const u16v8*)(qkv + h * 64 + half * 32 + c * 8);
        #pragma unroll
        for (int j = 0; j < 8; ++j) qf[c * 8 + j] = bf2f(v[j]);
    }
    float sc[8];
    #pragma unroll
    for (int g = 0; g < 8; ++g) {
        const unsigned short* kp = qkv + DIMC + g * 64 + half * 32;
        float a = 0.f;
        #pragma unroll
        for (int c = 0; c < 4; ++c) {
            u16v8 v = *(const u16v8*)(kp + c * 8);
            #pragma unroll
            for (int j = 0; j < 8; ++j) a = fmaf(qf[c * 8 + j], bf2f(v[j]), a);
        }
        a += __shfl_xor(a, 1);       // combine the two 32-dim halves
        sc[g] = a * 0.125f;
    }
    float mx = sc[0];
    #pragma unroll
    for (int g = 1; g < 8; ++g) mx = fmaxf(mx, sc[g]);
    float sum = 0.f;
    #pragma unroll
    for (int g = 0; g < 8; ++g) { sc[g] = __expf(sc[g] - mx); sum += sc[g]; }
    const float inv = 1.f / sum;
    #pragma unroll
    for (int g = 0; g < 8; ++g) sc[g] *= inv;

    float o[32] = {};
    #pragma unroll
    for (int g = 0; g < 8; ++g) {
        const unsigned short* vp = qkv + 2 * DIMC + g * 64 + half * 32;
        #pragma unroll
        for (int c = 0; c < 4; ++c) {
            u16v8 v = *(const u16v8*)(vp + c * 8);
            #pragma unroll
            for (int j = 0; j < 8; ++j) o[c * 8 + j] = fmaf(sc[g], bf2f(v[j]), o[c * 8 + j]);
        }
    }
    const int n = tok & (SEQ - 1);
    const int b = tok >> 12;
    const size_t drow = (size_t)b * SEQ + h * 512 + (n >> 3);
    unsigned short* dst = Y2 + drow * DIMC + ((n & 7) << 6) + half * 32;
    #pragma unroll
    for (int c = 0; c < 4; ++c) {
        u16v8 ov;
        #pragma unroll
        for (int j = 0; j < 8; ++j) ov[j] = f2bf(o[c * 8 + j]);
        *(u16v8*)(dst + c * 8) = ov;
    }
}

extern "C" void kernel_launch(void* const* d_in, const int* in_sizes, int n_in,
                              void* d_out, int out_size, void* d_ws, size_t ws_size,
                              hipStream_t stream) {
    const float* x     = (const float*)d_in[0];
    const float* qkv_w = (const float*)d_in[1];
    const float* qkv_b = (const float*)d_in[2];
    const float* out_w = (const float*)d_in[3];
    const float* out_b = (const float*)d_in[4];
    float* out = (float*)d_out;

    unsigned short* Y1 = (unsigned short*)d_ws;            // 50.3 MB
    unsigned short* Xb = Y1 + (size_t)M_TOK * N_QKV;       // 16.8 MB
    unsigned short* Y2 = Xb;   // overlay: Xb dead before attn_mix2 writes Y2
    unsigned short* Wq = Xb + (size_t)M_TOK * DIMC;
    unsigned short* Wo = Wq + (size_t)N_QKV * DIMC;

    cvt_all<<<(NX8 + NWQ8 + NWO8) / 256, 256, 0, stream>>>(x, qkv_w, out_w, Xb, Wq, Wo);

    gemm_nt_r3<true><<<dim3(M_TOK / 128, N_QKV / 256), 512, 0, stream>>>(
        Xb, Wq, qkv_b, Y1, M_TOK, N_QKV, DIMC);

    attn_mix2<<<M_TOK / 16, 256, 0, stream>>>(Y1, Y2);

    gemm_nt_r3<false><<<dim3(M_TOK / 128, DIMC / 256), 512, 0, stream>>>(
        Y2, Wo, out_b, out, M_TOK, DIMC, DIMC);
}